// Round 2
// baseline (409.388 us; speedup 1.0000x reference)
//
#include <hip/hip_runtime.h>

typedef __bf16 bf16;
typedef bf16 bf16x8 __attribute__((ext_vector_type(8)));
typedef bf16 bf16x4 __attribute__((ext_vector_type(4)));
typedef float f32x4 __attribute__((ext_vector_type(4)));

#define MFMA(a, b, c) __builtin_amdgcn_mfma_f32_16x16x32_bf16((a), (b), (c), 0, 0, 0)

// N=32, BSZ=512, NE=7, DIN=512, DH=256 ; M = N*BSZ*NE = 114688 rows
// out: marginal [32,512,7] = 114688 f32, joint [32,512,128] = 2097152 f32

// ---------------------------------------------------------------------------
// merged prep (blocks 0..97) + relation/bsum (blocks 98..609)
// prep: pack W0^T, W1^T, W2^T into MFMA A-fragment order (bf16).
// A-frag (16x16x32): lane l holds A[m = tile*16+(l&15)][k = kstep*32+(l>>4)*8+j]
// bsum: bsum[b][s] = sum_p bp3[b, p, bit_i(s)+bit_j(s)]  (s over 128 states)
// ---------------------------------------------------------------------------
__global__ __launch_bounds__(256) void k_prep_bsum(
    const float* __restrict__ W0, const float* __restrict__ W1,
    const float* __restrict__ W2, bf16* __restrict__ W0f,
    bf16* __restrict__ W1f, bf16* __restrict__ W2f,
    const float* __restrict__ ctx, const float* __restrict__ R0,
    const float* __restrict__ r0, const float* __restrict__ R1,
    const float* __restrict__ r1, float* __restrict__ bsum) {
  if (blockIdx.x < 98) {
    int g = blockIdx.x * 256 + threadIdx.x;
    if (g < 16384) {                       // W0^T: 16 mt x 16 ks x 64 lanes
      int mt = g >> 10, ks = (g >> 6) & 15, lane = g & 63;
      int m = mt * 16 + (lane & 15);
      int kb = ks * 32 + (lane >> 4) * 8;
      bf16x8 v;
#pragma unroll
      for (int j = 0; j < 8; ++j) v[j] = (bf16)W0[(kb + j) * 256 + m];
      *(bf16x8*)&W0f[g * 8] = v;
    } else if (g < 24576) {                // W1^T: 16 mt x 8 ks
      int h = g - 16384;
      int mt = h >> 9, ks = (h >> 6) & 7, lane = h & 63;
      int m = mt * 16 + (lane & 15);
      int kb = ks * 32 + (lane >> 4) * 8;
      bf16x8 v;
#pragma unroll
      for (int j = 0; j < 8; ++j) v[j] = (bf16)W1[(kb + j) * 256 + m];
      *(bf16x8*)&W1f[h * 8] = v;
    } else {                               // W2^T: 1 mt (rows 0,1 valid) x 8 ks
      int h = g - 24576;                   // 0..511
      int ks = h >> 6, lane = h & 63;
      int c = lane & 15;
      int kb = ks * 32 + (lane >> 4) * 8;
      bf16x8 v;
#pragma unroll
      for (int j = 0; j < 8; ++j) v[j] = (c < 2) ? (bf16)W2[(kb + j) * 2 + c] : (bf16)0.0f;
      *(bf16x8*)&W2f[h * 8] = v;
    }
  } else {
    __shared__ float ctx_l[105], R0_l[320], r0_l[64], R1_l[192], r1_l[3];
    __shared__ float h2[21 * 65];
    __shared__ float bp[63];
    const int t = threadIdx.x;
    const int b = blockIdx.x - 98;
    if (t < 105) ctx_l[t] = ctx[b * 105 + t];
    if (t < 64) r0_l[t] = r0[t];
    if (t < 192) R1_l[t] = R1[t];
    if (t < 3) r1_l[t] = r1[t];
    for (int i = t; i < 320; i += 256) R0_l[i] = R0[i];
    __syncthreads();
    for (int idx = t; idx < 1344; idx += 256) {
      int p = idx >> 6, u = idx & 63;
      float a = r0_l[u];
#pragma unroll
      for (int x = 0; x < 5; ++x) a += ctx_l[p * 5 + x] * R0_l[x * 64 + u];
      h2[p * 65 + u] = fmaxf(a, 0.f);
    }
    __syncthreads();
    if (t < 63) {
      int p = t / 3, y = t - p * 3;
      float a = r1_l[y];
      for (int u = 0; u < 64; ++u) a += h2[p * 65 + u] * R1_l[u * 3 + y];
      bp[t] = a;
    }
    __syncthreads();
    if (t < 128) {
      // state s = t; entity i bit = (s >> (6-i)) & 1 (entity 0 most significant)
      float a = 0.f;
      int pi = 0;
#pragma unroll
      for (int i = 0; i < 7; ++i)
#pragma unroll
        for (int j = i + 1; j < 7; ++j) {
          int bi = (t >> (6 - i)) & 1, bj = (t >> (6 - j)) & 1;
          a += bp[pi * 3 + bi + bj];
          ++pi;
        }
      bsum[b * 128 + t] = a;
    }
  }
}

// ---------------------------------------------------------------------------
// unary MLP, fused, transposed GEMMs. Block: 256 thr (4 waves), 64 rows.
//   D0 = W0^T(256x512) * X^T(512x64) -> h0 ; D1 = W1^T * h0^T -> h1 ; D2 -> un
// BK=64 (2 MFMA ksteps per staging iter), register-prefetch across barrier.
// LDS 47 KB -> 3 blocks/CU (launch_bounds(256,3) caps VGPR at ~170).
// ---------------------------------------------------------------------------
__global__ __launch_bounds__(256, 3) void k_unary(const float* __restrict__ input,
                                                  const bf16* __restrict__ W0f,
                                                  const bf16* __restrict__ W1f,
                                                  const bf16* __restrict__ W2f,
                                                  const float* __restrict__ b0,
                                                  const float* __restrict__ b1,
                                                  const float* __restrict__ b2,
                                                  float* __restrict__ un) {
  __shared__ bf16 inp_lds[64 * 68];    // 64 rows x BK=64 (+4 pad) bf16, 8.7 KB
  __shared__ bf16 h_lds[64 * 264];     // 64 rows x 256 (+8 pad) bf16, 33.8 KB
  __shared__ float bias_lds[512];
  __shared__ float part_lds[512];

  const int tid = threadIdx.x;
  const int wave = tid >> 6;
  const int lane = tid & 63;
  const int l16 = lane & 15;
  const int lq = lane >> 4;            // 0..3
  const long m0 = (long)blockIdx.x * 64;

  bias_lds[tid] = b0[tid];
  bias_lds[256 + tid] = b1[tid];

  f32x4 acc[4][4];
#pragma unroll
  for (int i = 0; i < 4; ++i)
#pragma unroll
    for (int j = 0; j < 4; ++j) acc[i][j] = (f32x4){0.f, 0.f, 0.f, 0.f};

  // staging map: thread -> (row r, 16-float chunk q); 64 B/thread/iter
  const int r = tid >> 2;              // 0..63
  const int q = tid & 3;               // 0..3
  const float* gp = input + (m0 + r) * 512 + q * 16;
  float4 x0 = ((const float4*)gp)[0];
  float4 x1 = ((const float4*)gp)[1];
  float4 x2 = ((const float4*)gp)[2];
  float4 x3 = ((const float4*)gp)[3];

  // ---- layer 0: K=512, 8 iters of BK=64 --------------------------------
  for (int it = 0; it < 8; ++it) {
    __syncthreads();
    bf16x8 wlo, whi;
    wlo[0] = (bf16)x0.x; wlo[1] = (bf16)x0.y; wlo[2] = (bf16)x0.z; wlo[3] = (bf16)x0.w;
    wlo[4] = (bf16)x1.x; wlo[5] = (bf16)x1.y; wlo[6] = (bf16)x1.z; wlo[7] = (bf16)x1.w;
    whi[0] = (bf16)x2.x; whi[1] = (bf16)x2.y; whi[2] = (bf16)x2.z; whi[3] = (bf16)x2.w;
    whi[4] = (bf16)x3.x; whi[5] = (bf16)x3.y; whi[6] = (bf16)x3.z; whi[7] = (bf16)x3.w;
    *(bf16x8*)&inp_lds[r * 68 + q * 16] = wlo;
    *(bf16x8*)&inp_lds[r * 68 + q * 16 + 8] = whi;
    __syncthreads();
    if (it < 7) {                      // prefetch next tile; hidden under MFMAs
      gp += 64;
      x0 = ((const float4*)gp)[0];
      x1 = ((const float4*)gp)[1];
      x2 = ((const float4*)gp)[2];
      x3 = ((const float4*)gp)[3];
    }
#pragma unroll
    for (int s = 0; s < 2; ++s) {
      bf16x8 bfr[4];
#pragma unroll
      for (int nt = 0; nt < 4; ++nt)
        bfr[nt] = *(const bf16x8*)&inp_lds[(nt * 16 + l16) * 68 + s * 32 + lq * 8];
#pragma unroll
      for (int mt = 0; mt < 4; ++mt) {
        bf16x8 a = *(const bf16x8*)&W0f[(((wave * 4 + mt) * 16 + it * 2 + s) * 64 + lane) * 8];
#pragma unroll
        for (int nt = 0; nt < 4; ++nt) acc[mt][nt] = MFMA(a, bfr[nt], acc[mt][nt]);
      }
    }
  }

  // epilogue 0: h0 = relu(D0 + b0) -> h_lds[m][n]
#pragma unroll
  for (int mt = 0; mt < 4; ++mt) {
    const int nbase = (wave * 4 + mt) * 16 + lq * 4;
    float bb[4];
#pragma unroll
    for (int g = 0; g < 4; ++g) bb[g] = bias_lds[nbase + g];
#pragma unroll
    for (int nt = 0; nt < 4; ++nt) {
      const int m = nt * 16 + l16;
      bf16x4 hv;
#pragma unroll
      for (int g = 0; g < 4; ++g) hv[g] = (bf16)fmaxf(acc[mt][nt][g] + bb[g], 0.f);
      *(bf16x4*)&h_lds[m * 264 + nbase] = hv;
    }
  }
  __syncthreads();

  // ---- layer 1: K=256, 8 ksteps ----------------------------------------
#pragma unroll
  for (int i = 0; i < 4; ++i)
#pragma unroll
    for (int j = 0; j < 4; ++j) acc[i][j] = (f32x4){0.f, 0.f, 0.f, 0.f};
#pragma unroll
  for (int ks = 0; ks < 8; ++ks) {
    bf16x8 bfr[4];
#pragma unroll
    for (int nt = 0; nt < 4; ++nt)
      bfr[nt] = *(const bf16x8*)&h_lds[(nt * 16 + l16) * 264 + ks * 32 + lq * 8];
#pragma unroll
    for (int mt = 0; mt < 4; ++mt) {
      bf16x8 a = *(const bf16x8*)&W1f[(((wave * 4 + mt) * 8 + ks) * 64 + lane) * 8];
#pragma unroll
      for (int nt = 0; nt < 4; ++nt) acc[mt][nt] = MFMA(a, bfr[nt], acc[mt][nt]);
    }
  }
  __syncthreads();   // everyone done reading h0 before overwrite

  // epilogue 1: h1 = relu(D1 + b1) -> h_lds[m][n]
#pragma unroll
  for (int mt = 0; mt < 4; ++mt) {
    const int nbase = (wave * 4 + mt) * 16 + lq * 4;
    float bb[4];
#pragma unroll
    for (int g = 0; g < 4; ++g) bb[g] = bias_lds[256 + nbase + g];
#pragma unroll
    for (int nt = 0; nt < 4; ++nt) {
      const int m = nt * 16 + l16;
      bf16x4 hv;
#pragma unroll
      for (int g = 0; g < 4; ++g) hv[g] = (bf16)fmaxf(acc[mt][nt][g] + bb[g], 0.f);
      *(bf16x4*)&h_lds[m * 264 + nbase] = hv;
    }
  }
  __syncthreads();

  // ---- layer 2: K=256 split across waves (2 ksteps each) ----------------
  f32x4 acc2[4];
#pragma unroll
  for (int i = 0; i < 4; ++i) acc2[i] = (f32x4){0.f, 0.f, 0.f, 0.f};
#pragma unroll
  for (int s = 0; s < 2; ++s) {
    const int ks = wave * 2 + s;
    bf16x8 a = *(const bf16x8*)&W2f[(ks * 64 + lane) * 8];
#pragma unroll
    for (int nt = 0; nt < 4; ++nt) {
      bf16x8 b = *(const bf16x8*)&h_lds[(nt * 16 + l16) * 264 + ks * 32 + lq * 8];
      acc2[nt] = MFMA(a, b, acc2[nt]);
    }
  }
  if (lane < 16) {   // valid rows c=0,1 live in regs 0,1 of lq==0 lanes
#pragma unroll
    for (int nt = 0; nt < 4; ++nt) {
      part_lds[((wave * 4 + nt) * 16 + lane) * 2 + 0] = acc2[nt][0];
      part_lds[((wave * 4 + nt) * 16 + lane) * 2 + 1] = acc2[nt][1];
    }
  }
  __syncthreads();
  if (tid < 128) {
    const int mloc = tid >> 1, c = tid & 1;
    const int nt = mloc >> 4, l = mloc & 15;
    float s = b2[c];
#pragma unroll
    for (int w2 = 0; w2 < 4; ++w2) s += part_lds[((w2 * 4 + nt) * 16 + l) * 2 + c];
    un[(m0 + mloc) * 2 + c] = s;
  }
}

// ---------------------------------------------------------------------------
// joint + marginals: ONE WAVE per (n,b) row; lane L holds states L and L+64
// (entity 0 = bit 6). No barriers, no LDS. Subtree-retention reduction:
// fold total t over bits 0..5; at step q capture u[q] = bit-q-set half, then
// co-fold u[j<q] -> 21 shuffles for {T, u[0..5]} (+6 for e1 sum, +6 for max).
// ---------------------------------------------------------------------------
__global__ __launch_bounds__(256) void k_joint(const float* __restrict__ un,
                                               const float* __restrict__ bsum,
                                               float* __restrict__ out_marg,
                                               float* __restrict__ out_joint) {
  const int lane = threadIdx.x & 63;
  const int wave = threadIdx.x >> 6;
  const int gw = blockIdx.x * 4 + wave;      // row = n*512 + b, 0..16383
  const int b = gw & 511;
  const long row = gw;
  const int urow = __builtin_amdgcn_readfirstlane(gw);   // uniform -> s_loads
  float u[14];
#pragma unroll
  for (int i = 0; i < 14; ++i) u[i] = un[(long)urow * 14 + i];
  const float bs0 = bsum[b * 128 + lane];
  const float bs1 = bsum[b * 128 + 64 + lane];
  float jc = 0.f;
#pragma unroll
  for (int i = 1; i < 7; ++i) jc += u[i * 2 + ((lane >> (6 - i)) & 1)];
  const float j0 = bs0 + jc + u[0];
  const float j1 = bs1 + jc + u[1];
  float m = fmaxf(j0, j1);
#pragma unroll
  for (int o = 1; o < 64; o <<= 1) m = fmaxf(m, __shfl_xor(m, o, 64));
  const float e0 = __expf(j0 - m), e1 = __expf(j1 - m);
  float t = e0 + e1;       // pair sum per lane
  float s1e = e1;          // entity-0 (bit 6) set-sum
  float uu[6];
#pragma unroll
  for (int q = 0; q < 6; ++q) {
    float pt = __shfl_xor(t, 1 << q, 64);
    uu[q] = ((lane >> q) & 1) ? t : pt;
    t += pt;
    s1e += __shfl_xor(s1e, 1 << q, 64);
#pragma unroll
    for (int jq = 0; jq < q; ++jq) uu[jq] += __shfl_xor(uu[jq], 1 << q, 64);
  }
  const float lZ = m + __logf(t);
  out_joint[row * 128 + lane] = j0 - lZ;
  out_joint[row * 128 + 64 + lane] = j1 - lZ;
  if (lane < 7) {
    // entity 0 -> s1e; entity i>=1 -> lane-bit q = 6-i -> uu[6-i]
    const float s1 = (lane == 0) ? s1e : uu[6 - lane];
    out_marg[row * 7 + lane] = __logf(s1) - __logf(t - s1);
  }
}

// ---------------------------------------------------------------------------
extern "C" void kernel_launch(void* const* d_in, const int* in_sizes, int n_in,
                              void* d_out, int out_size, void* d_ws, size_t ws_size,
                              hipStream_t stream) {
  const float* input = (const float*)d_in[0];
  const float* ctx   = (const float*)d_in[1];
  // d_in[2]=lang_input, d_in[3]=num_markables: unused by the reference
  const float* W0 = (const float*)d_in[4];
  const float* b0 = (const float*)d_in[5];
  const float* W1 = (const float*)d_in[6];
  const float* b1 = (const float*)d_in[7];
  const float* W2 = (const float*)d_in[8];
  const float* b2 = (const float*)d_in[9];
  const float* R0 = (const float*)d_in[10];
  const float* r0 = (const float*)d_in[11];
  const float* R1 = (const float*)d_in[12];
  const float* r1 = (const float*)d_in[13];

  char* ws = (char*)d_ws;
  bf16* W0f  = (bf16*)(ws + 0);         // 262144 B
  bf16* W1f  = (bf16*)(ws + 262144);    // 131072 B
  bf16* W2f  = (bf16*)(ws + 393216);    //   8192 B
  float* un  = (float*)(ws + 401408);   // 917504 B
  float* bsm = (float*)(ws + 1318912);  // 262144 B

  float* out_marg = (float*)d_out;
  float* out_joint = out_marg + 114688;

  hipLaunchKernelGGL(k_prep_bsum, dim3(610), dim3(256), 0, stream,
                     W0, W1, W2, W0f, W1f, W2f, ctx, R0, r0, R1, r1, bsm);
  hipLaunchKernelGGL(k_unary, dim3(1792), dim3(256), 0, stream,
                     input, W0f, W1f, W2f, b0, b1, b2, un);
  hipLaunchKernelGGL(k_joint, dim3(4096), dim3(256), 0, stream, un, bsm, out_marg, out_joint);
}

// Round 3
// 407.452 us; speedup vs baseline: 1.0048x; 1.0048x over previous
//
#include <hip/hip_runtime.h>

typedef __bf16 bf16;
typedef bf16 bf16x8 __attribute__((ext_vector_type(8)));
typedef bf16 bf16x4 __attribute__((ext_vector_type(4)));
typedef float f32x4 __attribute__((ext_vector_type(4)));

#define MFMA(a, b, c) __builtin_amdgcn_mfma_f32_16x16x32_bf16((a), (b), (c), 0, 0, 0)

// N=32, BSZ=512, NE=7, DIN=512, DH=256 ; M = N*BSZ*NE = 114688 rows
// out: marginal [32,512,7] = 114688 f32, joint [32,512,128] = 2097152 f32

// ---------------------------------------------------------------------------
// merged prep (blocks 0..97) + relation/bsum (blocks 98..609)
// prep: pack W0^T, W1^T, W2^T into MFMA A-fragment order (bf16).
// A-frag (16x16x32): lane l holds A[m = tile*16+(l&15)][k = kstep*32+(l>>4)*8+j]
// bsum: bsum[b][s] = sum_p bp3[b, p, bit_i(s)+bit_j(s)]  (s over 128 states)
// ---------------------------------------------------------------------------
__global__ __launch_bounds__(256) void k_prep_bsum(
    const float* __restrict__ W0, const float* __restrict__ W1,
    const float* __restrict__ W2, bf16* __restrict__ W0f,
    bf16* __restrict__ W1f, bf16* __restrict__ W2f,
    const float* __restrict__ ctx, const float* __restrict__ R0,
    const float* __restrict__ r0, const float* __restrict__ R1,
    const float* __restrict__ r1, float* __restrict__ bsum) {
  if (blockIdx.x < 98) {
    int g = blockIdx.x * 256 + threadIdx.x;
    if (g < 16384) {                       // W0^T: 16 mt x 16 ks x 64 lanes
      int mt = g >> 10, ks = (g >> 6) & 15, lane = g & 63;
      int m = mt * 16 + (lane & 15);
      int kb = ks * 32 + (lane >> 4) * 8;
      bf16x8 v;
#pragma unroll
      for (int j = 0; j < 8; ++j) v[j] = (bf16)W0[(kb + j) * 256 + m];
      *(bf16x8*)&W0f[g * 8] = v;
    } else if (g < 24576) {                // W1^T: 16 mt x 8 ks
      int h = g - 16384;
      int mt = h >> 9, ks = (h >> 6) & 7, lane = h & 63;
      int m = mt * 16 + (lane & 15);
      int kb = ks * 32 + (lane >> 4) * 8;
      bf16x8 v;
#pragma unroll
      for (int j = 0; j < 8; ++j) v[j] = (bf16)W1[(kb + j) * 256 + m];
      *(bf16x8*)&W1f[h * 8] = v;
    } else {                               // W2^T: 1 mt (rows 0,1 valid) x 8 ks
      int h = g - 24576;                   // 0..511
      int ks = h >> 6, lane = h & 63;
      int c = lane & 15;
      int kb = ks * 32 + (lane >> 4) * 8;
      bf16x8 v;
#pragma unroll
      for (int j = 0; j < 8; ++j) v[j] = (c < 2) ? (bf16)W2[(kb + j) * 2 + c] : (bf16)0.0f;
      *(bf16x8*)&W2f[h * 8] = v;
    }
  } else {
    __shared__ float ctx_l[105], R0_l[320], r0_l[64], R1_l[192], r1_l[3];
    __shared__ float h2[21 * 65];
    __shared__ float bp[63];
    const int t = threadIdx.x;
    const int b = blockIdx.x - 98;
    if (t < 105) ctx_l[t] = ctx[b * 105 + t];
    if (t < 64) r0_l[t] = r0[t];
    if (t < 192) R1_l[t] = R1[t];
    if (t < 3) r1_l[t] = r1[t];
    for (int i = t; i < 320; i += 256) R0_l[i] = R0[i];
    __syncthreads();
    for (int idx = t; idx < 1344; idx += 256) {
      int p = idx >> 6, u = idx & 63;
      float a = r0_l[u];
#pragma unroll
      for (int x = 0; x < 5; ++x) a += ctx_l[p * 5 + x] * R0_l[x * 64 + u];
      h2[p * 65 + u] = fmaxf(a, 0.f);
    }
    __syncthreads();
    if (t < 63) {
      int p = t / 3, y = t - p * 3;
      float a = r1_l[y];
      for (int u = 0; u < 64; ++u) a += h2[p * 65 + u] * R1_l[u * 3 + y];
      bp[t] = a;
    }
    __syncthreads();
    if (t < 128) {
      float a = 0.f;
      int pi = 0;
#pragma unroll
      for (int i = 0; i < 7; ++i)
#pragma unroll
        for (int j = i + 1; j < 7; ++j) {
          int bi = (t >> (6 - i)) & 1, bj = (t >> (6 - j)) & 1;
          a += bp[pi * 3 + bi + bj];
          ++pi;
        }
      bsum[b * 128 + t] = a;
    }
  }
}

// ---------------------------------------------------------------------------
// unary MLP, fused, transposed GEMMs. Block: 256 thr (4 waves), 64 rows.
// Layer0: K=512, BK=64, DOUBLE-BUFFERED staging, ONE barrier/iter; staging
// global loads are issued AFTER the barrier so no vm load is in flight at any
// s_barrier (the compiler's vmcnt(0) drain costs nothing); x-load latency is
// covered by one full compute phase (~1900 cyc >> 900 HBM).
// LDS: inp dbuf 2x(64x68) bf16 = 17408 B | h 64x264 bf16 = 33792 | bias 2048
//      part_lds overlaid on dead inp region. Total 53248 B -> 3 blocks/CU.
// ---------------------------------------------------------------------------
__global__ __launch_bounds__(256, 3) void k_unary(const float* __restrict__ input,
                                                  const bf16* __restrict__ W0f,
                                                  const bf16* __restrict__ W1f,
                                                  const bf16* __restrict__ W2f,
                                                  const float* __restrict__ b0,
                                                  const float* __restrict__ b1,
                                                  const float* __restrict__ b2,
                                                  float* __restrict__ un) {
  __shared__ __align__(16) char smem[53248];
  bf16* inp_lds = (bf16*)smem;                    // 2 x 4352 bf16
  bf16* h_lds = (bf16*)(smem + 17408);            // 64 x 264 bf16
  float* bias_lds = (float*)(smem + 51200);       // 512 f32
  float* part_lds = (float*)smem;                 // overlaid (inp dead by then)

  const int tid = threadIdx.x;
  const int wave = tid >> 6;
  const int lane = tid & 63;
  const int l16 = lane & 15;
  const int lq = lane >> 4;            // 0..3
  const int m0 = blockIdx.x * 64;

  bias_lds[tid] = b0[tid];
  bias_lds[256 + tid] = b1[tid];

  f32x4 acc[4][4];
#pragma unroll
  for (int i = 0; i < 4; ++i)
#pragma unroll
    for (int j = 0; j < 4; ++j) acc[i][j] = (f32x4){0.f, 0.f, 0.f, 0.f};

  // staging map: thread -> (row r, 16-float chunk q); 64 B/thread/iter
  const int r = tid >> 2;              // 0..63
  const int q = tid & 3;               // 0..3
  const float* gp = input + (m0 + r) * 512 + q * 16;
  float4 x0 = ((const float4*)gp)[0];
  float4 x1 = ((const float4*)gp)[1];
  float4 x2 = ((const float4*)gp)[2];
  float4 x3 = ((const float4*)gp)[3];

  // ---- layer 0: K=512, 8 iters of BK=64, dbuf, 1 barrier/iter ----------
  for (int it = 0; it < 8; ++it) {
    {  // convert & write tile it -> buf[it&1] (waits only on x loads)
      bf16x8 wlo, whi;
      wlo[0] = (bf16)x0.x; wlo[1] = (bf16)x0.y; wlo[2] = (bf16)x0.z; wlo[3] = (bf16)x0.w;
      wlo[4] = (bf16)x1.x; wlo[5] = (bf16)x1.y; wlo[6] = (bf16)x1.z; wlo[7] = (bf16)x1.w;
      whi[0] = (bf16)x2.x; whi[1] = (bf16)x2.y; whi[2] = (bf16)x2.z; whi[3] = (bf16)x2.w;
      whi[4] = (bf16)x3.x; whi[5] = (bf16)x3.y; whi[6] = (bf16)x3.z; whi[7] = (bf16)x3.w;
      bf16* dst = inp_lds + (it & 1) * 4352 + r * 68 + q * 16;
      *(bf16x8*)dst = wlo;
      *(bf16x8*)(dst + 8) = whi;
    }
    __syncthreads();                   // no vm loads in flight here
    if (it < 7) {                      // issue next tile's loads AFTER barrier
      gp += 64;
      x0 = ((const float4*)gp)[0];
      x1 = ((const float4*)gp)[1];
      x2 = ((const float4*)gp)[2];
      x3 = ((const float4*)gp)[3];
    }
    const bf16* buf = inp_lds + (it & 1) * 4352;
#pragma unroll
    for (int s = 0; s < 2; ++s) {
      bf16x8 bfr[4];
#pragma unroll
      for (int nt = 0; nt < 4; ++nt)
        bfr[nt] = *(const bf16x8*)&buf[(nt * 16 + l16) * 68 + s * 32 + lq * 8];
#pragma unroll
      for (int mt = 0; mt < 4; ++mt) {
        bf16x8 a = *(const bf16x8*)&W0f[(((wave * 4 + mt) * 16 + it * 2 + s) * 64 + lane) * 8];
#pragma unroll
        for (int nt = 0; nt < 4; ++nt) acc[mt][nt] = MFMA(a, bfr[nt], acc[mt][nt]);
      }
    }
  }
  __syncthreads();   // all layer-0 LDS reads done before h_lds epilogue? (h separate region; this orders inp reuse as part_lds later)

  // epilogue 0: h0 = relu(D0 + b0) -> h_lds[m][n]
#pragma unroll
  for (int mt = 0; mt < 4; ++mt) {
    const int nbase = (wave * 4 + mt) * 16 + lq * 4;
    float bb[4];
#pragma unroll
    for (int g = 0; g < 4; ++g) bb[g] = bias_lds[nbase + g];
#pragma unroll
    for (int nt = 0; nt < 4; ++nt) {
      const int m = nt * 16 + l16;
      bf16x4 hv;
#pragma unroll
      for (int g = 0; g < 4; ++g) hv[g] = (bf16)fmaxf(acc[mt][nt][g] + bb[g], 0.f);
      *(bf16x4*)&h_lds[m * 264 + nbase] = hv;
    }
  }
  __syncthreads();

  // ---- layer 1: K=256, 8 ksteps, no barriers ---------------------------
#pragma unroll
  for (int i = 0; i < 4; ++i)
#pragma unroll
    for (int j = 0; j < 4; ++j) acc[i][j] = (f32x4){0.f, 0.f, 0.f, 0.f};
#pragma unroll
  for (int ks = 0; ks < 8; ++ks) {
    bf16x8 bfr[4];
#pragma unroll
    for (int nt = 0; nt < 4; ++nt)
      bfr[nt] = *(const bf16x8*)&h_lds[(nt * 16 + l16) * 264 + ks * 32 + lq * 8];
#pragma unroll
    for (int mt = 0; mt < 4; ++mt) {
      bf16x8 a = *(const bf16x8*)&W1f[(((wave * 4 + mt) * 8 + ks) * 64 + lane) * 8];
#pragma unroll
      for (int nt = 0; nt < 4; ++nt) acc[mt][nt] = MFMA(a, bfr[nt], acc[mt][nt]);
    }
  }
  __syncthreads();   // everyone done reading h0 before overwrite

  // epilogue 1: h1 = relu(D1 + b1) -> h_lds[m][n]
#pragma unroll
  for (int mt = 0; mt < 4; ++mt) {
    const int nbase = (wave * 4 + mt) * 16 + lq * 4;
    float bb[4];
#pragma unroll
    for (int g = 0; g < 4; ++g) bb[g] = bias_lds[256 + nbase + g];
#pragma unroll
    for (int nt = 0; nt < 4; ++nt) {
      const int m = nt * 16 + l16;
      bf16x4 hv;
#pragma unroll
      for (int g = 0; g < 4; ++g) hv[g] = (bf16)fmaxf(acc[mt][nt][g] + bb[g], 0.f);
      *(bf16x4*)&h_lds[m * 264 + nbase] = hv;
    }
  }
  __syncthreads();

  // ---- layer 2: K=256 split across waves (2 ksteps each) ----------------
  f32x4 acc2[4];
#pragma unroll
  for (int i = 0; i < 4; ++i) acc2[i] = (f32x4){0.f, 0.f, 0.f, 0.f};
#pragma unroll
  for (int s = 0; s < 2; ++s) {
    const int ks = wave * 2 + s;
    bf16x8 a = *(const bf16x8*)&W2f[(ks * 64 + lane) * 8];
#pragma unroll
    for (int nt = 0; nt < 4; ++nt) {
      bf16x8 b = *(const bf16x8*)&h_lds[(nt * 16 + l16) * 264 + ks * 32 + lq * 8];
      acc2[nt] = MFMA(a, b, acc2[nt]);
    }
  }
  if (lane < 16) {   // valid rows c=0,1 live in regs 0,1 of lq==0 lanes
#pragma unroll
    for (int nt = 0; nt < 4; ++nt) {
      part_lds[((wave * 4 + nt) * 16 + lane) * 2 + 0] = acc2[nt][0];
      part_lds[((wave * 4 + nt) * 16 + lane) * 2 + 1] = acc2[nt][1];
    }
  }
  __syncthreads();
  if (tid < 128) {
    const int mloc = tid >> 1, c = tid & 1;
    const int nt = mloc >> 4, l = mloc & 15;
    float s = b2[c];
#pragma unroll
    for (int w2 = 0; w2 < 4; ++w2) s += part_lds[((w2 * 4 + nt) * 16 + l) * 2 + c];
    un[(m0 + mloc) * 2 + c] = s;
  }
}

// ---------------------------------------------------------------------------
// joint + marginals: ONE WAVE per (n,b) row; lane L holds states L and L+64
// (entity 0 = bit 6). No barriers, no LDS. Subtree-retention reduction.
// ---------------------------------------------------------------------------
__global__ __launch_bounds__(256) void k_joint(const float* __restrict__ un,
                                               const float* __restrict__ bsum,
                                               float* __restrict__ out_marg,
                                               float* __restrict__ out_joint) {
  const int lane = threadIdx.x & 63;
  const int wave = threadIdx.x >> 6;
  const int gw = blockIdx.x * 4 + wave;      // row = n*512 + b, 0..16383
  const int b = gw & 511;
  const long row = gw;
  const int urow = __builtin_amdgcn_readfirstlane(gw);   // uniform -> s_loads
  float u[14];
#pragma unroll
  for (int i = 0; i < 14; ++i) u[i] = un[(long)urow * 14 + i];
  const float bs0 = bsum[b * 128 + lane];
  const float bs1 = bsum[b * 128 + 64 + lane];
  float jc = 0.f;
#pragma unroll
  for (int i = 1; i < 7; ++i) jc += u[i * 2 + ((lane >> (6 - i)) & 1)];
  const float j0 = bs0 + jc + u[0];
  const float j1 = bs1 + jc + u[1];
  float m = fmaxf(j0, j1);
#pragma unroll
  for (int o = 1; o < 64; o <<= 1) m = fmaxf(m, __shfl_xor(m, o, 64));
  const float e0 = __expf(j0 - m), e1 = __expf(j1 - m);
  float t = e0 + e1;       // pair sum per lane
  float s1e = e1;          // entity-0 (bit 6) set-sum
  float uu[6];
#pragma unroll
  for (int q = 0; q < 6; ++q) {
    float pt = __shfl_xor(t, 1 << q, 64);
    uu[q] = ((lane >> q) & 1) ? t : pt;
    t += pt;
    s1e += __shfl_xor(s1e, 1 << q, 64);
#pragma unroll
    for (int jq = 0; jq < q; ++jq) uu[jq] += __shfl_xor(uu[jq], 1 << q, 64);
  }
  const float lZ = m + __logf(t);
  out_joint[row * 128 + lane] = j0 - lZ;
  out_joint[row * 128 + 64 + lane] = j1 - lZ;
  if (lane < 7) {
    const float s1 = (lane == 0) ? s1e : uu[6 - lane];
    out_marg[row * 7 + lane] = __logf(s1) - __logf(t - s1);
  }
}

// ---------------------------------------------------------------------------
extern "C" void kernel_launch(void* const* d_in, const int* in_sizes, int n_in,
                              void* d_out, int out_size, void* d_ws, size_t ws_size,
                              hipStream_t stream) {
  const float* input = (const float*)d_in[0];
  const float* ctx   = (const float*)d_in[1];
  // d_in[2]=lang_input, d_in[3]=num_markables: unused by the reference
  const float* W0 = (const float*)d_in[4];
  const float* b0 = (const float*)d_in[5];
  const float* W1 = (const float*)d_in[6];
  const float* b1 = (const float*)d_in[7];
  const float* W2 = (const float*)d_in[8];
  const float* b2 = (const float*)d_in[9];
  const float* R0 = (const float*)d_in[10];
  const float* r0 = (const float*)d_in[11];
  const float* R1 = (const float*)d_in[12];
  const float* r1 = (const float*)d_in[13];

  char* ws = (char*)d_ws;
  bf16* W0f  = (bf16*)(ws + 0);         // 262144 B
  bf16* W1f  = (bf16*)(ws + 262144);    // 131072 B
  bf16* W2f  = (bf16*)(ws + 393216);    //   8192 B
  float* un  = (float*)(ws + 401408);   // 917504 B
  float* bsm = (float*)(ws + 1318912);  // 262144 B

  float* out_marg = (float*)d_out;
  float* out_joint = out_marg + 114688;

  hipLaunchKernelGGL(k_prep_bsum, dim3(610), dim3(256), 0, stream,
                     W0, W1, W2, W0f, W1f, W2f, ctx, R0, r0, R1, r1, bsm);
  hipLaunchKernelGGL(k_unary, dim3(1792), dim3(256), 0, stream,
                     input, W0f, W1f, W2f, b0, b1, b2, un);
  hipLaunchKernelGGL(k_joint, dim3(4096), dim3(256), 0, stream, un, bsm, out_marg, out_joint);
}